// Round 2
// baseline (20340.955 us; speedup 1.0000x reference)
//
#include <hip/hip_runtime.h>
#include <math.h>

typedef unsigned short u16;
typedef unsigned int   u32;
typedef __attribute__((ext_vector_type(8))) short short8;
typedef __attribute__((ext_vector_type(4))) float f32x4;

__device__ __forceinline__ float bf2f(u16 v) { return __uint_as_float(((u32)v) << 16); }
__device__ __forceinline__ u16 f2bf(float f) {
    u32 u = __float_as_uint(f);
    u32 r = (u + 0x7fffu + ((u >> 16) & 1u)) >> 16;
    return (u16)r;
}
__device__ __forceinline__ u32 pk2(float a, float b) {
    return ((u32)f2bf(a)) | (((u32)f2bf(b)) << 16);
}
__device__ __forceinline__ float sigm(float x) { return 1.f / (1.f + __expf(-x)); }
__device__ __forceinline__ f32x4 mfma16(short8 a, short8 b, f32x4 c) {
    return __builtin_amdgcn_mfma_f32_16x16x32_bf16(a, b, c, 0, 0, 0);
}
__device__ __forceinline__ short8 ld8bf(const float* p) {
    short8 r;
#pragma unroll
    for (int j = 0; j < 8; ++j) r[j] = (short)f2bf(p[j]);
    return r;
}

#define FLAG_STRIDE 16 /* ints -> 64B per flag slot */
#define YF 0           /* y_frame fp32 base in d_out */
#define XL_OFF 16384000
#define PS_OFF 16384016

// ---------------------------------------------------------------------------
// Persistent 3-layer frame LSTM. 192 WGs (64 per layer), 128 threads each.
// WG owns 8 h-cols (32 gate rows); weights live in registers as bf16
// B-fragments (converted from the fp32 inputs once at start).
// Layers software-pipelined; flag barrier each global step.
// h state double-buffered bf16 in ws; layer-2 h also stored fp32 to d_out.
// ---------------------------------------------------------------------------
template<int KTIN, bool L0>
__device__ __forceinline__ void frame_body(
    const int layer, const int kwg, const int wgid,
    const float* __restrict__ Wih, const float* __restrict__ Whh, const float* __restrict__ bias,
    const float* __restrict__ x, u16* __restrict__ hbuf, int* __restrict__ flags,
    float* __restrict__ h3out, float* sC, float* scs, u16* sxpad)
{
    const int tid  = threadIdx.x;
    const int lane = tid & 63;
    const int wave = tid >> 6;
    const int n16  = lane & 15;
    const int quad = lane >> 4;
    const int koff = quad * 8;

    if (tid < 128) scs[tid] = 0.f;                // c-state (16 batch x 8 cols) fp32
    if (L0) {                                     // zero the x pad cols [80,96)
        for (int e = tid; e < 256; e += 128) sxpad[(e >> 4) * 96 + 80 + (e & 15)] = 0;
    }

    // B fragments in registers. wave0 -> tile (i|f), wave1 -> tile (g|o).
    const int grow = wave * 1024 + ((n16 >> 3) * 512) + kwg * 8 + (n16 & 7);
    short8 bfr[KTIN + 16];
#pragma unroll
    for (int kt = 0; kt < KTIN; ++kt) {
        short8 v = {0,0,0,0,0,0,0,0};
        const int k = kt * 32 + koff;
        if (L0) { if (k + 8 <= 80) v = ld8bf(Wih + grow * 80 + k); }
        else    { v = ld8bf(Wih + (size_t)grow * 512 + k); }
        bfr[kt] = v;
    }
#pragma unroll
    for (int kt = 0; kt < 16; ++kt)
        bfr[KTIN + kt] = ld8bf(Whh + (size_t)grow * 512 + kt * 32 + koff);

    const int pb = (tid >> 4) & 3;
    const int cb = kwg * 8 + pb * 2;
    const float bI0 = bias[cb],        bI1 = bias[cb + 1];
    const float bF0 = bias[512 + cb],  bF1 = bias[512 + cb + 1];
    const float bG0 = bias[1024 + cb], bG1 = bias[1024 + cb + 1];
    const float bO0 = bias[1536 + cb], bO1 = bias[1536 + cb + 1];
    __syncthreads();

    const int aoff = n16 * 512 + koff;

    for (int u = 0; u < 2002; ++u) {
        const int t = u - layer;
        const bool act = (t >= 0) && (t < 2000);
        if (act) {
            if (L0) {  // stage x_t (16x80 fp32) into padded bf16 LDS (16x96)
                for (int e = tid; e < 320; e += 128) {
                    const int bb = e / 20;
                    const int q = e - bb * 20;
                    const float4 v = *(const float4*)(x + ((size_t)bb * 2000 + t) * 80 + q * 4);
                    u32* d = (u32*)(sxpad + bb * 96 + q * 4);
                    d[0] = pk2(v.x, v.y);
                    d[1] = pk2(v.z, v.w);
                }
                __syncthreads();
            }
            f32x4 acc[4] = {{0,0,0,0},{0,0,0,0},{0,0,0,0},{0,0,0,0}};
            const u16* hown = hbuf + ((layer * 2 + ((t & 1) ^ 1)) << 13);
#pragma unroll
            for (int kt = 0; kt < KTIN; ++kt) {
                short8 a;
                if (L0) a = *(const short8*)(sxpad + n16 * 96 + koff + kt * 32);
                else {
                    const u16* hin = hbuf + (((layer - 1) * 2 + (t & 1)) << 13);
                    a = *(const short8*)(hin + aoff + kt * 32);
                }
                acc[kt & 3] = mfma16(a, bfr[kt], acc[kt & 3]);
            }
#pragma unroll
            for (int kt = 0; kt < 16; ++kt) {
                short8 a = *(const short8*)(hown + aoff + kt * 32);
                acc[(KTIN + kt) & 3] = mfma16(a, bfr[KTIN + kt], acc[(KTIN + kt) & 3]);
            }
            const f32x4 C = acc[0] + acc[1] + acc[2] + acc[3];
#pragma unroll
            for (int r = 0; r < 4; ++r)
                sC[(wave * 16 + quad * 4 + r) * 16 + n16] = C[r];   // [tile][batch][gate]
            __syncthreads();
            if (tid < 64) {  // gate math + publish h slice (wave0 only)
                const int b = tid & 15, p = tid >> 4;
                u32 pk = 0;
#pragma unroll
                for (int e = 0; e < 2; ++e) {
                    const int jl = p * 2 + e;
                    const float gi = sC[b * 16 + jl]            + (e ? bI1 : bI0);
                    const float gf = sC[b * 16 + 8 + jl]        + (e ? bF1 : bF0);
                    const float gg = sC[(16 + b) * 16 + jl]     + (e ? bG1 : bG0);
                    const float go = sC[(16 + b) * 16 + 8 + jl] + (e ? bO1 : bO0);
                    const float cp = scs[b * 8 + jl];
                    const float cn = sigm(gf) * cp + sigm(gi) * tanhf(gg);
                    const float hn = sigm(go) * tanhf(cn);
                    scs[b * 8 + jl] = cn;
                    pk |= ((u32)f2bf(hn)) << (16 * e);
                    if (!L0 && layer == 2)
                        h3out[((size_t)(b * 2000 + t)) * 512 + kwg * 8 + p * 2 + e] = hn;
                }
                u32* hdst = (u32*)(hbuf + ((layer * 2 + (t & 1)) << 13) + b * 512 + kwg * 8 + p * 2);
                __hip_atomic_store(hdst, pk, __ATOMIC_RELAXED, __HIP_MEMORY_SCOPE_AGENT);
            }
        }
        // ---- global step barrier (flag per WG, padded to 64B) ----
        if (wave == 0) {
            if (lane == 0)
                __hip_atomic_store(flags + wgid * FLAG_STRIDE, u + 1, __ATOMIC_RELEASE, __HIP_MEMORY_SCOPE_AGENT);
            const int i0 = lane * 3;
            int guard = 0;
            for (;;) {
                const int f0 = __hip_atomic_load(flags + (i0 + 0) * FLAG_STRIDE, __ATOMIC_RELAXED, __HIP_MEMORY_SCOPE_AGENT);
                const int f1 = __hip_atomic_load(flags + (i0 + 1) * FLAG_STRIDE, __ATOMIC_RELAXED, __HIP_MEMORY_SCOPE_AGENT);
                const int f2 = __hip_atomic_load(flags + (i0 + 2) * FLAG_STRIDE, __ATOMIC_RELAXED, __HIP_MEMORY_SCOPE_AGENT);
                if (__all((f0 > u) && (f1 > u) && (f2 > u))) break;
                if (++guard > (1 << 22)) break;   // anti-hang escape
                __builtin_amdgcn_s_sleep(1);
            }
        }
        __syncthreads();
        __builtin_amdgcn_fence(__ATOMIC_ACQUIRE, "agent");  // invalidate stale caches before next A loads
    }
}

__global__ __launch_bounds__(128, 1) void k_frame_lstm(
    const float* __restrict__ x,
    const float* __restrict__ Wih0, const float* __restrict__ Whh0, const float* __restrict__ b0,
    const float* __restrict__ Wih1, const float* __restrict__ Whh1, const float* __restrict__ b1,
    const float* __restrict__ Wih2, const float* __restrict__ Whh2, const float* __restrict__ b2,
    u16* hbuf, int* flags, float* h3out)
{
    __shared__ __align__(16) u16 sxpad[16 * 96];
    __shared__ float sC[2 * 16 * 16];
    __shared__ float scs[16 * 8];
    const int wgid = blockIdx.x;
    const int layer = wgid >> 6;
    const int kwg = wgid & 63;
    if (layer == 0)      frame_body<3,  true >(0, kwg, wgid, Wih0, Whh0, b0, x, hbuf, flags, h3out, sC, scs, sxpad);
    else if (layer == 1) frame_body<16, false>(1, kwg, wgid, Wih1, Whh1, b1, x, hbuf, flags, h3out, sC, scs, sxpad);
    else                 frame_body<16, false>(2, kwg, wgid, Wih2, Whh2, b2, x, hbuf, flags, h3out, sC, scs, sxpad);
}

// ---------------------------------------------------------------------------
// Persistent word LSTM: 32 WGs x 128 threads, 100 steps, H=256, K=256+256.
// rW input is bf16 (ws). hseq output fp32 (ws).
// ---------------------------------------------------------------------------
__global__ __launch_bounds__(128, 1) void k_word_lstm(
    const u16* __restrict__ rW, const float* __restrict__ Wih,
    const float* __restrict__ Whh, const float* __restrict__ bias,
    u16* __restrict__ hbufw, int* __restrict__ flags, float* __restrict__ hseq)
{
    __shared__ float sC[2 * 16 * 16];
    __shared__ float scs[16 * 8];
    const int tid = threadIdx.x;
    const int lane = tid & 63;
    const int wave = tid >> 6;
    const int n16 = lane & 15;
    const int quad = lane >> 4;
    const int koff = quad * 8;
    const int kwg = blockIdx.x;  // 0..31

    if (tid < 128) scs[tid] = 0.f;
    const int grow = wave * 512 + ((n16 >> 3) * 256) + kwg * 8 + (n16 & 7);
    short8 bfr[16];
#pragma unroll
    for (int kt = 0; kt < 8; ++kt) bfr[kt]     = ld8bf(Wih + (size_t)grow * 256 + kt * 32 + koff);
#pragma unroll
    for (int kt = 0; kt < 8; ++kt) bfr[8 + kt] = ld8bf(Whh + (size_t)grow * 256 + kt * 32 + koff);
    const int pb = (tid >> 4) & 3;
    const int cb = kwg * 8 + pb * 2;
    const float bI0 = bias[cb],       bI1 = bias[cb + 1];
    const float bF0 = bias[256 + cb], bF1 = bias[256 + cb + 1];
    const float bG0 = bias[512 + cb], bG1 = bias[512 + cb + 1];
    const float bO0 = bias[768 + cb], bO1 = bias[768 + cb + 1];
    __syncthreads();
    const int aoff = n16 * 256 + koff;

    for (int t = 0; t < 100; ++t) {
        f32x4 acc[4] = {{0,0,0,0},{0,0,0,0},{0,0,0,0},{0,0,0,0}};
        const u16* hown = hbufw + (((t & 1) ^ 1) << 12);
#pragma unroll
        for (int kt = 0; kt < 8; ++kt) {
            short8 a = *(const short8*)(rW + ((size_t)(n16 * 100 + t)) * 256 + koff + kt * 32);
            acc[kt & 3] = mfma16(a, bfr[kt], acc[kt & 3]);
        }
#pragma unroll
        for (int kt = 0; kt < 8; ++kt) {
            short8 a = *(const short8*)(hown + aoff + kt * 32);
            acc[kt & 3] = mfma16(a, bfr[8 + kt], acc[kt & 3]);
        }
        const f32x4 C = acc[0] + acc[1] + acc[2] + acc[3];
#pragma unroll
        for (int r = 0; r < 4; ++r) sC[(wave * 16 + quad * 4 + r) * 16 + n16] = C[r];
        __syncthreads();
        if (tid < 64) {
            const int b = tid & 15, p = tid >> 4;
            u32 pk = 0;
#pragma unroll
            for (int e = 0; e < 2; ++e) {
                const int jl = p * 2 + e;
                const float gi = sC[b * 16 + jl]            + (e ? bI1 : bI0);
                const float gf = sC[b * 16 + 8 + jl]        + (e ? bF1 : bF0);
                const float gg = sC[(16 + b) * 16 + jl]     + (e ? bG1 : bG0);
                const float go = sC[(16 + b) * 16 + 8 + jl] + (e ? bO1 : bO0);
                const float cp = scs[b * 8 + jl];
                const float cn = sigm(gf) * cp + sigm(gi) * tanhf(gg);
                const float hn = sigm(go) * tanhf(cn);
                scs[b * 8 + jl] = cn;
                pk |= ((u32)f2bf(hn)) << (16 * e);
                hseq[((size_t)(b * 100 + t)) * 256 + kwg * 8 + p * 2 + e] = hn;
            }
            u32* hdst = (u32*)(hbufw + ((t & 1) << 12) + b * 256 + kwg * 8 + p * 2);
            __hip_atomic_store(hdst, pk, __ATOMIC_RELAXED, __HIP_MEMORY_SCOPE_AGENT);
        }
        if (wave == 0) {
            if (lane == 0)
                __hip_atomic_store(flags + (192 + kwg) * FLAG_STRIDE, t + 1, __ATOMIC_RELEASE, __HIP_MEMORY_SCOPE_AGENT);
            int guard = 0;
            for (;;) {
                const int f0 = (lane < 32)
                    ? __hip_atomic_load(flags + (192 + lane) * FLAG_STRIDE, __ATOMIC_RELAXED, __HIP_MEMORY_SCOPE_AGENT)
                    : 0x7fffffff;
                if (__all(f0 > t)) break;
                if (++guard > (1 << 22)) break;
                __builtin_amdgcn_s_sleep(1);
            }
        }
        __syncthreads();
        __builtin_amdgcn_fence(__ATOMIC_ACQUIRE, "agent");
    }
}

// ---------------------------------------------------------------------------
// Ragged tail-mean pooling from fp32 h3 (in d_out): reps fp32 (ws)
// ---------------------------------------------------------------------------
__global__ void k_pool(const float* __restrict__ h3, const int* __restrict__ x_lens,
                       const int* __restrict__ wstarts, const int* __restrict__ wends,
                       const int* __restrict__ wlens, const int* __restrict__ tailp,
                       float* __restrict__ reps)
{
    const int rw = blockIdx.x;
    const int b = rw / 100, w = rw - b * 100;
    const int tid = threadIdx.x;
    const int xl = x_lens[b];
    const int we = wends[rw];
    const int s0 = wstarts[rw];
    const int wl = wlens[b];
    const int tail = tailp[0];
    int ef = we < xl ? we : xl;
    int sf = s0 > 0 ? s0 : 0;
    int i0 = ef - tail; if (i0 < sf) i0 = sf;
    const bool valid = (w < wl) && (we > 0) && (ef > sf) && (ef > i0);
    float a0 = 0.f, a1 = 0.f;
    if (valid) {
        for (int t = i0; t < ef; ++t) {
            const float* hp = h3 + ((size_t)(b * 2000 + t)) * 512;
            a0 += hp[tid];
            a1 += hp[tid + 256];
        }
        const float inv = 1.f / (float)(ef - i0);
        a0 *= inv; a1 *= inv;
    }
    reps[(size_t)rw * 512 + tid] = a0;
    reps[(size_t)rw * 512 + tid + 256] = a1;
}

// ---------------------------------------------------------------------------
// In-place frame projection: y[b,t,:] = mask(h3[b,t,:]) @ fpW^T + fpb (fp32)
// Block = 16 rows staged to bf16 LDS first (in-place safe), 4 waves x 8 tiles.
// Weights read from pre-cast bf16 fpWb (ws).
// ---------------------------------------------------------------------------
__global__ __launch_bounds__(256, 2) void k_frame_proj(
    float* __restrict__ y, const int* __restrict__ x_lens,
    const u16* __restrict__ fpWb, const float* __restrict__ fpb)
{
    __shared__ __align__(16) u16 As[16 * 520];
    const int tid = threadIdx.x, lane = tid & 63, wave = tid >> 6;
    const int n16 = lane & 15, quad = lane >> 4, koff = quad * 8;
    const int blk = blockIdx.x;          // 2000 blocks: 125 per batch
    const int b = blk / 125;
    const int t0 = (blk - b * 125) * 16;
    const int xl = x_lens[b];
    for (int c = tid; c < 2048; c += 256) {      // 16 rows x 128 float4
        const int row = c >> 7;
        const int q = c & 127;
        const int t = t0 + row;
        float4 v = {0.f, 0.f, 0.f, 0.f};
        if (t < xl) v = *(const float4*)(y + ((size_t)(b * 2000 + t)) * 512 + q * 4);
        u32* d = (u32*)(As + row * 520 + q * 4);
        d[0] = pk2(v.x, v.y);
        d[1] = pk2(v.z, v.w);
    }
    __syncthreads();
    const size_t rowbase = (size_t)b * 2000 + t0;
    for (int ct = 0; ct < 8; ++ct) {
        const int col0 = (wave * 8 + ct) * 16;
        f32x4 acc = {0, 0, 0, 0};
#pragma unroll
        for (int kt = 0; kt < 16; ++kt) {
            short8 a = *(const short8*)(As + n16 * 520 + kt * 32 + koff);
            short8 wv = *(const short8*)(fpWb + ((size_t)(col0 + n16)) * 512 + kt * 32 + koff);
            acc = mfma16(a, wv, acc);
        }
        const float bn = fpb[col0 + n16];
#pragma unroll
        for (int r = 0; r < 4; ++r) {
            const int m = quad * 4 + r;
            y[(rowbase + m) * 512 + col0 + n16] = acc[r] + bn;
        }
    }
}

// ---------------------------------------------------------------------------
// word_proj: Linear(512->256) + LayerNorm + exact GELU per (b,w) row.
// reps fp32 -> rW bf16 (word-LSTM A operand format).
// ---------------------------------------------------------------------------
__global__ void k_word_proj(const float* __restrict__ reps, const float* __restrict__ wpW,
                            const float* __restrict__ wpb, const float* __restrict__ lnW,
                            const float* __restrict__ lnB, u16* __restrict__ rW)
{
    __shared__ float sx[512];
    __shared__ float red[512];
    const int tid = threadIdx.x;
    const int row = blockIdx.x;
    for (int k = tid; k < 512; k += 256) sx[k] = reps[(size_t)row * 512 + k];
    __syncthreads();
    float acc = wpb[tid];
    const float4* wr = (const float4*)(wpW + (size_t)tid * 512);
    for (int k4 = 0; k4 < 128; ++k4) {
        const float4 w = wr[k4];
        acc += sx[k4 * 4] * w.x + sx[k4 * 4 + 1] * w.y + sx[k4 * 4 + 2] * w.z + sx[k4 * 4 + 3] * w.w;
    }
    red[tid] = acc; red[256 + tid] = acc * acc;
    __syncthreads();
    for (int s = 128; s > 0; s >>= 1) {
        if (tid < s) { red[tid] += red[tid + s]; red[256 + tid] += red[256 + tid + s]; }
        __syncthreads();
    }
    const float mu = red[0] * (1.f / 256.f);
    float var = red[256] * (1.f / 256.f) - mu * mu;
    if (var < 0.f) var = 0.f;
    const float xn = (acc - mu) * rsqrtf(var + 1e-5f);
    const float yv = xn * lnW[tid] + lnB[tid];
    const float g = 0.5f * yv * (1.0f + erff(yv * 0.70710678118654752f));
    rW[(size_t)row * 256 + tid] = f2bf(g);
}

// ---------------------------------------------------------------------------
// pred_sem = mask(hseq) @ spW^T + spb  (all fp32 vector math)
// ---------------------------------------------------------------------------
__global__ void k_pred(const float* __restrict__ hseq, const int* __restrict__ wlens,
                       const float* __restrict__ spW, const float* __restrict__ spb,
                       float* __restrict__ out)
{
    __shared__ float sh[256];
    const int tid = threadIdx.x;
    const int rw = blockIdx.x;
    const int b = rw / 100, w = rw - b * 100;
    int wl = wlens[b]; if (wl < 1) wl = 1;
    const bool valid = (w < wl);
    sh[tid] = valid ? hseq[(size_t)rw * 256 + tid] : 0.f;
    __syncthreads();
    for (int o = tid; o < 512; o += 256) {
        float acc = spb[o];
        const float4* wr = (const float4*)(spW + (size_t)o * 256);
        for (int k4 = 0; k4 < 64; ++k4) {
            const float4 wv = wr[k4];
            acc += sh[k4 * 4] * wv.x + sh[k4 * 4 + 1] * wv.y + sh[k4 * 4 + 2] * wv.z + sh[k4 * 4 + 3] * wv.w;
        }
        out[PS_OFF + (size_t)rw * 512 + o] = acc;
    }
}

__global__ void k_xlens(const int* __restrict__ x_lens, float* __restrict__ out)
{
    const int tid = threadIdx.x;
    if (tid < 16) out[XL_OFF + tid] = (float)x_lens[tid];
}

// Pre-cast fpW (512x512 fp32) -> bf16
__global__ void k_cvt(const float* __restrict__ src, u16* __restrict__ dst)
{
    const int e = blockIdx.x * 256 + threadIdx.x;   // 65536 float4s
    const float4 v = *(const float4*)(src + (size_t)e * 4);
    u32* d = (u32*)(dst + (size_t)e * 4);
    d[0] = pk2(v.x, v.y);
    d[1] = pk2(v.z, v.w);
}

__global__ void k_zero(u32* __restrict__ p)
{
    p[blockIdx.x * 256 + threadIdx.x] = 0u;   // 128 blocks x 256 = 131072 B
}

// ---------------------------------------------------------------------------
extern "C" void kernel_launch(void* const* d_in, const int* in_sizes, int n_in,
                              void* d_out, int out_size, void* d_ws, size_t ws_size,
                              hipStream_t stream)
{
    (void)in_sizes; (void)n_in; (void)out_size; (void)ws_size;
    const float* x    = (const float*)d_in[0];
    const int* x_lens = (const int*)d_in[1];
    const int* wstart = (const int*)d_in[2];
    const int* wend   = (const int*)d_in[3];
    const int* wlen   = (const int*)d_in[4];
    const int* tailp  = (const int*)d_in[5];
    const float* Wih0 = (const float*)d_in[6];
    const float* Whh0 = (const float*)d_in[7];
    const float* b0   = (const float*)d_in[8];
    const float* Wih1 = (const float*)d_in[9];
    const float* Whh1 = (const float*)d_in[10];
    const float* b1   = (const float*)d_in[11];
    const float* Wih2 = (const float*)d_in[12];
    const float* Whh2 = (const float*)d_in[13];
    const float* b2   = (const float*)d_in[14];
    const float* fpW  = (const float*)d_in[15];
    const float* fpb  = (const float*)d_in[16];
    const float* wpW  = (const float*)d_in[17];
    const float* wpb  = (const float*)d_in[18];
    const float* lnW  = (const float*)d_in[19];
    const float* lnB  = (const float*)d_in[20];
    const float* wWih = (const float*)d_in[21];
    const float* wWhh = (const float*)d_in[22];
    const float* wb   = (const float*)d_in[23];
    const float* spW  = (const float*)d_in[24];
    const float* spb  = (const float*)d_in[25];

    float* out = (float*)d_out;
    char* ws = (char*)d_ws;
    int* flags  = (int*)ws;                    //       0 .. 16384   (256 x 64B flag slots)
    u16* hbufF  = (u16*)(ws + 16384);          //   16384 .. 114688  (3 layers x 2 parity x 16x512 bf16)
    u16* hbufW  = (u16*)(ws + 114688);         //  114688 .. 131072  (2 parity x 16x256 bf16)
    float* reps = (float*)(ws + 131072);       //  1600 x 512 fp32   (3.27 MB)
    u16* rW     = (u16*)(ws + 3407872);        //  1600 x 256 bf16   (0.82 MB)
    float* hseq = (float*)(ws + 4227072);      //  1600 x 256 fp32   (1.64 MB)
    u16* fpWb   = (u16*)(ws + 5865472);        //  512 x 512 bf16    (0.52 MB)

    k_zero<<<128, 256, 0, stream>>>((u32*)d_ws);
    k_cvt<<<256, 256, 0, stream>>>(fpW, fpWb);
    k_frame_lstm<<<192, 128, 0, stream>>>(x, Wih0, Whh0, b0, Wih1, Whh1, b1,
                                          Wih2, Whh2, b2, hbufF, flags, out);
    k_pool<<<1600, 256, 0, stream>>>(out, x_lens, wstart, wend, wlen, tailp, reps);
    k_frame_proj<<<2000, 256, 0, stream>>>(out, x_lens, fpWb, fpb);  // after k_pool (in-place)
    k_word_proj<<<1600, 256, 0, stream>>>(reps, wpW, wpb, lnW, lnB, rW);
    k_word_lstm<<<32, 128, 0, stream>>>(rW, wWih, wWhh, wb, hbufW, flags, hseq);
    k_pred<<<1600, 256, 0, stream>>>(hseq, wlen, spW, spb, out);
    k_xlens<<<1, 64, 0, stream>>>(x_lens, out);
}

// Round 3
// 13345.576 us; speedup vs baseline: 1.5242x; 1.5242x over previous
//
#include <hip/hip_runtime.h>
#include <math.h>

typedef unsigned short u16;
typedef unsigned int   u32;
typedef unsigned long long u64;
typedef __attribute__((ext_vector_type(8))) short short8;
typedef __attribute__((ext_vector_type(4))) float f32x4;

__device__ __forceinline__ float bf2f(u16 v) { return __uint_as_float(((u32)v) << 16); }
__device__ __forceinline__ u16 f2bf(float f) {
    u32 u = __float_as_uint(f);
    u32 r = (u + 0x7fffu + ((u >> 16) & 1u)) >> 16;
    return (u16)r;
}
__device__ __forceinline__ u32 pk2(float a, float b) {
    return ((u32)f2bf(a)) | (((u32)f2bf(b)) << 16);
}
__device__ __forceinline__ float sigm(float x) { return 1.f / (1.f + __expf(-x)); }
__device__ __forceinline__ f32x4 mfma16(short8 a, short8 b, f32x4 c) {
    return __builtin_amdgcn_mfma_f32_16x16x32_bf16(a, b, c, 0, 0, 0);
}
__device__ __forceinline__ short8 ld8bf(const float* p) {
    short8 r;
#pragma unroll
    for (int j = 0; j < 8; ++j) r[j] = (short)f2bf(p[j]);
    return r;
}
// 16B cache-bypassing load (agent-scope relaxed atomics -> sc0 sc1, no fence)
__device__ __forceinline__ short8 ldq16(const u16* p) {
    u64 lo = __hip_atomic_load((const u64*)p,       __ATOMIC_RELAXED, __HIP_MEMORY_SCOPE_AGENT);
    u64 hi = __hip_atomic_load((const u64*)(p + 4), __ATOMIC_RELAXED, __HIP_MEMORY_SCOPE_AGENT);
    union { u64 q[2]; short8 v; } uu;
    uu.q[0] = lo; uu.q[1] = hi;
    return uu.v;
}
__device__ __forceinline__ void vm_drain() {
    asm volatile("s_waitcnt vmcnt(0)" ::: "memory");
}

#define FLAG_STRIDE 16 /* ints -> 64B per flag slot */
#define XL_OFF 16384000
#define PS_OFF 16384016

// ---------------------------------------------------------------------------
// Persistent 3-layer frame LSTM. 192 WGs (64 per layer), 128 threads each.
// WG owns 8 h-cols (32 gate rows); weights live in registers as bf16
// B-fragments. Layers software-pipelined; flag barrier each global step.
// NO fences in the loop: all cross-WG state moves via sc0/sc1 bypass atomics;
// store->flag ordering via s_waitcnt vmcnt(0).
// ---------------------------------------------------------------------------
template<int KTIN, bool L0>
__device__ __forceinline__ void frame_body(
    const int layer, const int kwg, const int wgid,
    const float* __restrict__ Wih, const float* __restrict__ Whh, const float* __restrict__ bias,
    const float* __restrict__ x, u16* __restrict__ hbuf, int* __restrict__ flags,
    float* __restrict__ h3out, float* sC, float* scs, u16* sxpad)
{
    const int tid  = threadIdx.x;
    const int lane = tid & 63;
    const int wave = tid >> 6;
    const int n16  = lane & 15;
    const int quad = lane >> 4;
    const int koff = quad * 8;

    if (tid < 128) scs[tid] = 0.f;                // c-state (16 batch x 8 cols) fp32
    if (L0) {                                     // zero the x pad cols [80,96)
        for (int e = tid; e < 256; e += 128) sxpad[(e >> 4) * 96 + 80 + (e & 15)] = 0;
    }

    // B fragments in registers. wave0 -> tile (i|f), wave1 -> tile (g|o).
    const int grow = wave * 1024 + ((n16 >> 3) * 512) + kwg * 8 + (n16 & 7);
    short8 bfr[KTIN + 16];
#pragma unroll
    for (int kt = 0; kt < KTIN; ++kt) {
        short8 v = {0,0,0,0,0,0,0,0};
        const int k = kt * 32 + koff;
        if (L0) { if (k + 8 <= 80) v = ld8bf(Wih + grow * 80 + k); }
        else    { v = ld8bf(Wih + (size_t)grow * 512 + k); }
        bfr[kt] = v;
    }
#pragma unroll
    for (int kt = 0; kt < 16; ++kt)
        bfr[KTIN + kt] = ld8bf(Whh + (size_t)grow * 512 + kt * 32 + koff);

    const int pb = (tid >> 4) & 3;
    const int cb = kwg * 8 + pb * 2;
    const float bI0 = bias[cb],        bI1 = bias[cb + 1];
    const float bF0 = bias[512 + cb],  bF1 = bias[512 + cb + 1];
    const float bG0 = bias[1024 + cb], bG1 = bias[1024 + cb + 1];
    const float bO0 = bias[1536 + cb], bO1 = bias[1536 + cb + 1];
    __syncthreads();

    const int aoff = n16 * 512 + koff;

    for (int u = 0; u < 2002; ++u) {
        const int t = u - layer;
        const bool act = (t >= 0) && (t < 2000);
        if (act) {
            if (L0) {  // stage x_t (16x80 fp32) into padded bf16 LDS (16x96)
                for (int e = tid; e < 320; e += 128) {
                    const int bb = e / 20;
                    const int q = e - bb * 20;
                    const float4 v = *(const float4*)(x + ((size_t)bb * 2000 + t) * 80 + q * 4);
                    u32* d = (u32*)(sxpad + bb * 96 + q * 4);
                    d[0] = pk2(v.x, v.y);
                    d[1] = pk2(v.z, v.w);
                }
                __syncthreads();
            }
            f32x4 acc[4] = {{0,0,0,0},{0,0,0,0},{0,0,0,0},{0,0,0,0}};
            const u16* hown = hbuf + ((layer * 2 + ((t & 1) ^ 1)) << 13);
            const u16* hin  = hbuf + (((layer - 1) * 2 + (t & 1)) << 13);
#pragma unroll
            for (int kt = 0; kt < KTIN; ++kt) {
                short8 a;
                if (L0) a = *(const short8*)(sxpad + n16 * 96 + koff + kt * 32);
                else    a = ldq16(hin + aoff + kt * 32);
                acc[kt & 3] = mfma16(a, bfr[kt], acc[kt & 3]);
            }
#pragma unroll
            for (int kt = 0; kt < 16; ++kt) {
                short8 a = ldq16(hown + aoff + kt * 32);
                acc[(KTIN + kt) & 3] = mfma16(a, bfr[KTIN + kt], acc[(KTIN + kt) & 3]);
            }
            const f32x4 C = acc[0] + acc[1] + acc[2] + acc[3];
#pragma unroll
            for (int r = 0; r < 4; ++r)
                sC[(wave * 16 + quad * 4 + r) * 16 + n16] = C[r];   // [tile][batch][gate]
            __syncthreads();
            if (tid < 64) {  // gate math + publish h slice (wave0 only)
                const int b = tid & 15, p = tid >> 4;
                u32 pk = 0;
#pragma unroll
                for (int e = 0; e < 2; ++e) {
                    const int jl = p * 2 + e;
                    const float gi = sC[b * 16 + jl]            + (e ? bI1 : bI0);
                    const float gf = sC[b * 16 + 8 + jl]        + (e ? bF1 : bF0);
                    const float gg = sC[(16 + b) * 16 + jl]     + (e ? bG1 : bG0);
                    const float go = sC[(16 + b) * 16 + 8 + jl] + (e ? bO1 : bO0);
                    const float cp = scs[b * 8 + jl];
                    const float cn = sigm(gf) * cp + sigm(gi) * tanhf(gg);
                    const float hn = sigm(go) * tanhf(cn);
                    scs[b * 8 + jl] = cn;
                    pk |= ((u32)f2bf(hn)) << (16 * e);
                    if (!L0 && layer == 2)
                        h3out[((size_t)(b * 2000 + t)) * 512 + kwg * 8 + p * 2 + e] = hn;
                }
                u32* hdst = (u32*)(hbuf + ((layer * 2 + (t & 1)) << 13) + b * 512 + kwg * 8 + p * 2);
                __hip_atomic_store(hdst, pk, __ATOMIC_RELAXED, __HIP_MEMORY_SCOPE_AGENT);
            }
        }
        // ---- global step barrier: drain stores, then relaxed flag ----
        vm_drain();
        if (wave == 0) {
            if (lane == 0)
                __hip_atomic_store(flags + wgid * FLAG_STRIDE, u + 1, __ATOMIC_RELAXED, __HIP_MEMORY_SCOPE_AGENT);
            const int i0 = lane * 3;
            int guard = 0;
            for (;;) {
                const int f0 = __hip_atomic_load(flags + (i0 + 0) * FLAG_STRIDE, __ATOMIC_RELAXED, __HIP_MEMORY_SCOPE_AGENT);
                const int f1 = __hip_atomic_load(flags + (i0 + 1) * FLAG_STRIDE, __ATOMIC_RELAXED, __HIP_MEMORY_SCOPE_AGENT);
                const int f2 = __hip_atomic_load(flags + (i0 + 2) * FLAG_STRIDE, __ATOMIC_RELAXED, __HIP_MEMORY_SCOPE_AGENT);
                if (__all((f0 > u) && (f1 > u) && (f2 > u))) break;
                if (++guard > (1 << 22)) break;   // anti-hang escape
                __builtin_amdgcn_s_sleep(1);
            }
        }
        __syncthreads();
    }
}

__global__ __launch_bounds__(128, 1) void k_frame_lstm(
    const float* __restrict__ x,
    const float* __restrict__ Wih0, const float* __restrict__ Whh0, const float* __restrict__ b0,
    const float* __restrict__ Wih1, const float* __restrict__ Whh1, const float* __restrict__ b1,
    const float* __restrict__ Wih2, const float* __restrict__ Whh2, const float* __restrict__ b2,
    u16* hbuf, int* flags, float* h3out)
{
    __shared__ __align__(16) u16 sxpad[16 * 96];
    __shared__ float sC[2 * 16 * 16];
    __shared__ float scs[16 * 8];
    const int wgid = blockIdx.x;
    const int layer = wgid >> 6;
    const int kwg = wgid & 63;
    if (layer == 0)      frame_body<3,  true >(0, kwg, wgid, Wih0, Whh0, b0, x, hbuf, flags, h3out, sC, scs, sxpad);
    else if (layer == 1) frame_body<16, false>(1, kwg, wgid, Wih1, Whh1, b1, x, hbuf, flags, h3out, sC, scs, sxpad);
    else                 frame_body<16, false>(2, kwg, wgid, Wih2, Whh2, b2, x, hbuf, flags, h3out, sC, scs, sxpad);
}

// ---------------------------------------------------------------------------
// Persistent word LSTM: 32 WGs x 128 threads, 100 steps, H=256, K=256+256.
// rW input bf16 (ws, prior kernel). hseq output fp32 (ws). Fence-free barrier.
// ---------------------------------------------------------------------------
__global__ __launch_bounds__(128, 1) void k_word_lstm(
    const u16* __restrict__ rW, const float* __restrict__ Wih,
    const float* __restrict__ Whh, const float* __restrict__ bias,
    u16* __restrict__ hbufw, int* __restrict__ flags, float* __restrict__ hseq)
{
    __shared__ float sC[2 * 16 * 16];
    __shared__ float scs[16 * 8];
    const int tid = threadIdx.x;
    const int lane = tid & 63;
    const int wave = tid >> 6;
    const int n16 = lane & 15;
    const int quad = lane >> 4;
    const int koff = quad * 8;
    const int kwg = blockIdx.x;  // 0..31

    if (tid < 128) scs[tid] = 0.f;
    const int grow = wave * 512 + ((n16 >> 3) * 256) + kwg * 8 + (n16 & 7);
    short8 bfr[16];
#pragma unroll
    for (int kt = 0; kt < 8; ++kt) bfr[kt]     = ld8bf(Wih + (size_t)grow * 256 + kt * 32 + koff);
#pragma unroll
    for (int kt = 0; kt < 8; ++kt) bfr[8 + kt] = ld8bf(Whh + (size_t)grow * 256 + kt * 32 + koff);
    const int pb = (tid >> 4) & 3;
    const int cb = kwg * 8 + pb * 2;
    const float bI0 = bias[cb],       bI1 = bias[cb + 1];
    const float bF0 = bias[256 + cb], bF1 = bias[256 + cb + 1];
    const float bG0 = bias[512 + cb], bG1 = bias[512 + cb + 1];
    const float bO0 = bias[768 + cb], bO1 = bias[768 + cb + 1];
    __syncthreads();
    const int aoff = n16 * 256 + koff;

    for (int t = 0; t < 100; ++t) {
        f32x4 acc[4] = {{0,0,0,0},{0,0,0,0},{0,0,0,0},{0,0,0,0}};
        const u16* hown = hbufw + (((t & 1) ^ 1) << 12);
#pragma unroll
        for (int kt = 0; kt < 8; ++kt) {
            short8 a = *(const short8*)(rW + ((size_t)(n16 * 100 + t)) * 256 + koff + kt * 32);
            acc[kt & 3] = mfma16(a, bfr[kt], acc[kt & 3]);
        }
#pragma unroll
        for (int kt = 0; kt < 8; ++kt) {
            short8 a = ldq16(hown + aoff + kt * 32);
            acc[kt & 3] = mfma16(a, bfr[8 + kt], acc[kt & 3]);
        }
        const f32x4 C = acc[0] + acc[1] + acc[2] + acc[3];
#pragma unroll
        for (int r = 0; r < 4; ++r) sC[(wave * 16 + quad * 4 + r) * 16 + n16] = C[r];
        __syncthreads();
        if (tid < 64) {
            const int b = tid & 15, p = tid >> 4;
            u32 pk = 0;
#pragma unroll
            for (int e = 0; e < 2; ++e) {
                const int jl = p * 2 + e;
                const float gi = sC[b * 16 + jl]            + (e ? bI1 : bI0);
                const float gf = sC[b * 16 + 8 + jl]        + (e ? bF1 : bF0);
                const float gg = sC[(16 + b) * 16 + jl]     + (e ? bG1 : bG0);
                const float go = sC[(16 + b) * 16 + 8 + jl] + (e ? bO1 : bO0);
                const float cp = scs[b * 8 + jl];
                const float cn = sigm(gf) * cp + sigm(gi) * tanhf(gg);
                const float hn = sigm(go) * tanhf(cn);
                scs[b * 8 + jl] = cn;
                pk |= ((u32)f2bf(hn)) << (16 * e);
                hseq[((size_t)(b * 100 + t)) * 256 + kwg * 8 + p * 2 + e] = hn;
            }
            u32* hdst = (u32*)(hbufw + ((t & 1) << 12) + b * 256 + kwg * 8 + p * 2);
            __hip_atomic_store(hdst, pk, __ATOMIC_RELAXED, __HIP_MEMORY_SCOPE_AGENT);
        }
        vm_drain();
        if (wave == 0) {
            if (lane == 0)
                __hip_atomic_store(flags + (192 + kwg) * FLAG_STRIDE, t + 1, __ATOMIC_RELAXED, __HIP_MEMORY_SCOPE_AGENT);
            int guard = 0;
            for (;;) {
                const int f0 = (lane < 32)
                    ? __hip_atomic_load(flags + (192 + lane) * FLAG_STRIDE, __ATOMIC_RELAXED, __HIP_MEMORY_SCOPE_AGENT)
                    : 0x7fffffff;
                if (__all(f0 > t)) break;
                if (++guard > (1 << 22)) break;
                __builtin_amdgcn_s_sleep(1);
            }
        }
        __syncthreads();
    }
}

// ---------------------------------------------------------------------------
// Ragged tail-mean pooling from fp32 h3 (in d_out): reps fp32 (ws)
// ---------------------------------------------------------------------------
__global__ void k_pool(const float* __restrict__ h3, const int* __restrict__ x_lens,
                       const int* __restrict__ wstarts, const int* __restrict__ wends,
                       const int* __restrict__ wlens, const int* __restrict__ tailp,
                       float* __restrict__ reps)
{
    const int rw = blockIdx.x;
    const int b = rw / 100, w = rw - b * 100;
    const int tid = threadIdx.x;
    const int xl = x_lens[b];
    const int we = wends[rw];
    const int s0 = wstarts[rw];
    const int wl = wlens[b];
    const int tail = tailp[0];
    int ef = we < xl ? we : xl;
    int sf = s0 > 0 ? s0 : 0;
    int i0 = ef - tail; if (i0 < sf) i0 = sf;
    const bool valid = (w < wl) && (we > 0) && (ef > sf) && (ef > i0);
    float a0 = 0.f, a1 = 0.f;
    if (valid) {
        for (int t = i0; t < ef; ++t) {
            const float* hp = h3 + ((size_t)(b * 2000 + t)) * 512;
            a0 += hp[tid];
            a1 += hp[tid + 256];
        }
        const float inv = 1.f / (float)(ef - i0);
        a0 *= inv; a1 *= inv;
    }
    reps[(size_t)rw * 512 + tid] = a0;
    reps[(size_t)rw * 512 + tid + 256] = a1;
}

// ---------------------------------------------------------------------------
// In-place frame projection: y[b,t,:] = mask(h3[b,t,:]) @ fpW^T + fpb (fp32)
// Block = 16 rows staged to bf16 LDS first (in-place safe), 4 waves x 8 tiles.
// ---------------------------------------------------------------------------
__global__ __launch_bounds__(256, 2) void k_frame_proj(
    float* __restrict__ y, const int* __restrict__ x_lens,
    const u16* __restrict__ fpWb, const float* __restrict__ fpb)
{
    __shared__ __align__(16) u16 As[16 * 520];
    const int tid = threadIdx.x, lane = tid & 63, wave = tid >> 6;
    const int n16 = lane & 15, quad = lane >> 4, koff = quad * 8;
    const int blk = blockIdx.x;          // 2000 blocks: 125 per batch
    const int b = blk / 125;
    const int t0 = (blk - b * 125) * 16;
    const int xl = x_lens[b];
    for (int c = tid; c < 2048; c += 256) {      // 16 rows x 128 float4
        const int row = c >> 7;
        const int q = c & 127;
        const int t = t0 + row;
        float4 v = {0.f, 0.f, 0.f, 0.f};
        if (t < xl) v = *(const float4*)(y + ((size_t)(b * 2000 + t)) * 512 + q * 4);
        u32* d = (u32*)(As + row * 520 + q * 4);
        d[0] = pk2(v.x, v.y);
        d[1] = pk2(v.z, v.w);
    }
    __syncthreads();
    const size_t rowbase = (size_t)b * 2000 + t0;
    for (int ct = 0; ct < 8; ++ct) {
        const int col0 = (wave * 8 + ct) * 16;
        f32x4 acc = {0, 0, 0, 0};
#pragma unroll
        for (int kt = 0; kt < 16; ++kt) {
            short8 a = *(const short8*)(As + n16 * 520 + kt * 32 + koff);
            short8 wv = *(const short8*)(fpWb + ((size_t)(col0 + n16)) * 512 + kt * 32 + koff);
            acc = mfma16(a, wv, acc);
        }
        const float bn = fpb[col0 + n16];
#pragma unroll
        for (int r = 0; r < 4; ++r) {
            const int m = quad * 4 + r;
            y[(rowbase + m) * 512 + col0 + n16] = acc[r] + bn;
        }
    }
}

// ---------------------------------------------------------------------------
// word_proj: Linear(512->256) + LayerNorm + exact GELU per (b,w) row.
// ---------------------------------------------------------------------------
__global__ void k_word_proj(const float* __restrict__ reps, const float* __restrict__ wpW,
                            const float* __restrict__ wpb, const float* __restrict__ lnW,
                            const float* __restrict__ lnB, u16* __restrict__ rW)
{
    __shared__ float sx[512];
    __shared__ float red[512];
    const int tid = threadIdx.x;
    const int row = blockIdx.x;
    for (int k = tid; k < 512; k += 256) sx[k] = reps[(size_t)row * 512 + k];
    __syncthreads();
    float acc = wpb[tid];
    const float4* wr = (const float4*)(wpW + (size_t)tid * 512);
    for (int k4 = 0; k4 < 128; ++k4) {
        const float4 w = wr[k4];
        acc += sx[k4 * 4] * w.x + sx[k4 * 4 + 1] * w.y + sx[k4 * 4 + 2] * w.z + sx[k4 * 4 + 3] * w.w;
    }
    red[tid] = acc; red[256 + tid] = acc * acc;
    __syncthreads();
    for (int s = 128; s > 0; s >>= 1) {
        if (tid < s) { red[tid] += red[tid + s]; red[256 + tid] += red[256 + tid + s]; }
        __syncthreads();
    }
    const float mu = red[0] * (1.f / 256.f);
    float var = red[256] * (1.f / 256.f) - mu * mu;
    if (var < 0.f) var = 0.f;
    const float xn = (acc - mu) * rsqrtf(var + 1e-5f);
    const float yv = xn * lnW[tid] + lnB[tid];
    const float g = 0.5f * yv * (1.0f + erff(yv * 0.70710678118654752f));
    rW[(size_t)row * 256 + tid] = f2bf(g);
}

// ---------------------------------------------------------------------------
// pred_sem = mask(hseq) @ spW^T + spb  (fp32 vector math)
// ---------------------------------------------------------------------------
__global__ void k_pred(const float* __restrict__ hseq, const int* __restrict__ wlens,
                       const float* __restrict__ spW, const float* __restrict__ spb,
                       float* __restrict__ out)
{
    __shared__ float sh[256];
    const int tid = threadIdx.x;
    const int rw = blockIdx.x;
    const int b = rw / 100, w = rw - b * 100;
    int wl = wlens[b]; if (wl < 1) wl = 1;
    const bool valid = (w < wl);
    sh[tid] = valid ? hseq[(size_t)rw * 256 + tid] : 0.f;
    __syncthreads();
    for (int o = tid; o < 512; o += 256) {
        float acc = spb[o];
        const float4* wr = (const float4*)(spW + (size_t)o * 256);
        for (int k4 = 0; k4 < 64; ++k4) {
            const float4 wv = wr[k4];
            acc += sh[k4 * 4] * wv.x + sh[k4 * 4 + 1] * wv.y + sh[k4 * 4 + 2] * wv.z + sh[k4 * 4 + 3] * wv.w;
        }
        out[PS_OFF + (size_t)rw * 512 + o] = acc;
    }
}

__global__ void k_xlens(const int* __restrict__ x_lens, float* __restrict__ out)
{
    const int tid = threadIdx.x;
    if (tid < 16) out[XL_OFF + tid] = (float)x_lens[tid];
}

// Pre-cast fpW (512x512 fp32) -> bf16
__global__ void k_cvt(const float* __restrict__ src, u16* __restrict__ dst)
{
    const int e = blockIdx.x * 256 + threadIdx.x;   // 65536 float4s
    const float4 v = *(const float4*)(src + (size_t)e * 4);
    u32* d = (u32*)(dst + (size_t)e * 4);
    d[0] = pk2(v.x, v.y);
    d[1] = pk2(v.z, v.w);
}

__global__ void k_zero(u32* __restrict__ p)
{
    p[blockIdx.x * 256 + threadIdx.x] = 0u;   // 128 blocks x 256 = 131072 B
}

// ---------------------------------------------------------------------------
extern "C" void kernel_launch(void* const* d_in, const int* in_sizes, int n_in,
                              void* d_out, int out_size, void* d_ws, size_t ws_size,
                              hipStream_t stream)
{
    (void)in_sizes; (void)n_in; (void)out_size; (void)ws_size;
    const float* x    = (const float*)d_in[0];
    const int* x_lens = (const int*)d_in[1];
    const int* wstart = (const int*)d_in[2];
    const int* wend   = (const int*)d_in[3];
    const int* wlen   = (const int*)d_in[4];
    const int* tailp  = (const int*)d_in[5];
    const float* Wih0 = (const float*)d_in[6];
    const float* Whh0 = (const float*)d_in[7];
    const float* b0   = (const float*)d_in[8];
    const float* Wih1 = (const float*)d_in[9];
    const float* Whh1 = (const float*)d_in[10];
    const float* b1   = (const float*)d_in[11];
    const float* Wih2 = (const float*)d_in[12];
    const float* Whh2 = (const float*)d_in[13];
    const float* b2   = (const float*)d_in[14];
    const float* fpW  = (const float*)d_in[15];
    const float* fpb  = (const float*)d_in[16];
    const float* wpW  = (const float*)d_in[17];
    const float* wpb  = (const float*)d_in[18];
    const float* lnW  = (const float*)d_in[19];
    const float* lnB  = (const float*)d_in[20];
    const float* wWih = (const float*)d_in[21];
    const float* wWhh = (const float*)d_in[22];
    const float* wb   = (const float*)d_in[23];
    const float* spW  = (const float*)d_in[24];
    const float* spb  = (const float*)d_in[25];

    float* out = (float*)d_out;
    char* ws = (char*)d_ws;
    int* flags  = (int*)ws;                    //       0 .. 16384   (256 x 64B flag slots)
    u16* hbufF  = (u16*)(ws + 16384);          //   16384 .. 114688  (3 layers x 2 parity x 16x512 bf16)
    u16* hbufW  = (u16*)(ws + 114688);         //  114688 .. 131072  (2 parity x 16x256 bf16)
    float* reps = (float*)(ws + 131072);       //  1600 x 512 fp32   (3.27 MB)
    u16* rW     = (u16*)(ws + 3407872);        //  1600 x 256 bf16   (0.82 MB)
    float* hseq = (float*)(ws + 4227072);      //  1600 x 256 fp32   (1.64 MB)
    u16* fpWb   = (u16*)(ws + 5865472);        //  512 x 512 bf16    (0.52 MB)

    k_zero<<<128, 256, 0, stream>>>((u32*)d_ws);
    k_cvt<<<256, 256, 0, stream>>>(fpW, fpWb);
    k_frame_lstm<<<192, 128, 0, stream>>>(x, Wih0, Whh0, b0, Wih1, Whh1, b1,
                                          Wih2, Whh2, b2, hbufF, flags, out);
    k_pool<<<1600, 256, 0, stream>>>(out, x_lens, wstart, wend, wlen, tailp, reps);
    k_frame_proj<<<2000, 256, 0, stream>>>(out, x_lens, fpWb, fpb);  // after k_pool (in-place)
    k_word_proj<<<1600, 256, 0, stream>>>(reps, wpW, wpb, lnW, lnB, rW);
    k_word_lstm<<<32, 128, 0, stream>>>(rW, wWih, wWhh, wb, hbufW, flags, hseq);
    k_pred<<<1600, 256, 0, stream>>>(hseq, wlen, spW, spb, out);
    k_xlens<<<1, 64, 0, stream>>>(x_lens, out);
}

// Round 4
// 7719.019 us; speedup vs baseline: 2.6352x; 1.7289x over previous
//
#include <hip/hip_runtime.h>
#include <math.h>

typedef unsigned short u16;
typedef unsigned int   u32;
typedef unsigned long long u64;
typedef __attribute__((ext_vector_type(8))) short short8;
typedef __attribute__((ext_vector_type(4))) float f32x4;

__device__ __forceinline__ float bf2f(u16 v) { return __uint_as_float(((u32)v) << 16); }
__device__ __forceinline__ u16 f2bf(float f) {
    u32 u = __float_as_uint(f);
    u32 r = (u + 0x7fffu + ((u >> 16) & 1u)) >> 16;
    return (u16)r;
}
__device__ __forceinline__ u32 pk2(float a, float b) {
    return ((u32)f2bf(a)) | (((u32)f2bf(b)) << 16);
}
__device__ __forceinline__ float sigm(float x) { return 1.f / (1.f + __expf(-x)); }
__device__ __forceinline__ f32x4 mfma16(short8 a, short8 b, f32x4 c) {
    return __builtin_amdgcn_mfma_f32_16x16x32_bf16(a, b, c, 0, 0, 0);
}
__device__ __forceinline__ short8 ld8bf(const float* p) {
    short8 r;
#pragma unroll
    for (int j = 0; j < 8; ++j) r[j] = (short)f2bf(p[j]);
    return r;
}
// 16B cache-bypassing load straight to/from the IF$ coherence point.
__device__ __forceinline__ short8 ldg16cv(const u16* p) {
    short8 r;
    asm volatile("global_load_dwordx4 %0, %1, off sc0 sc1" : "=v"(r) : "v"(p));
    return r;
}
__device__ __forceinline__ void waitvm() {
    asm volatile("s_waitcnt vmcnt(0)" ::: "memory");
}

#define FLAG_STRIDE 16   /* ints -> 64B per flag slot */
#define NPAR 8           /* h ring depth */
#define BIGF (1 << 26)
#define XL_OFF 16384000
#define PS_OFF 16384016

// ws layout (bytes)
#define WS_FLAGS   0        /* 352 slots x 64B = 22528, padded to 32768 */
#define WS_HBUF_F  32768    /* 3 layers x 8 par x 16x512 bf16 = 393216 */
#define WS_HBUF_W  425984   /* 8 par x 16x256 bf16 = 65536 */
#define WS_REPS    491520   /* 1600x512 fp32 = 3276800 */
#define WS_RW      3768320  /* 1600x256 bf16 = 819200 */
#define WS_HSEQ    4587520  /* 1600x256 fp32 = 1638400 */
#define WS_FPWB    6225920  /* 512x512 bf16 = 524288 -> end 6750208 */

// ---------------------------------------------------------------------------
// Persistent 3-layer frame LSTM. 192 WGs (64 per layer), 128 threads each.
// WG owns 8 h-cols (32 gate rows); weights in registers as bf16 B-fragments.
// Producer/consumer flags + 8-deep ring: no global barrier, no fences.
// Per step: 16x16B bypass loads/lane -> LDS (deduped across waves) -> MFMA.
// ---------------------------------------------------------------------------
template<int KTIN, bool L0>
__device__ __forceinline__ void frame_body(
    const int layer, const int kwg,
    const float* __restrict__ Wih, const float* __restrict__ Whh, const float* __restrict__ bias,
    const float* __restrict__ x, u16* __restrict__ hbuf, int* __restrict__ flags,
    float* __restrict__ h3out, float* sC, float* scs, u16* sxpad, u16* AsIn, u16* AsOwn)
{
    const int tid  = threadIdx.x;
    const int lane = tid & 63;
    const int wave = tid >> 6;
    const int n16  = lane & 15;
    const int quad = lane >> 4;
    const int koff = quad * 8;

    for (int e = tid; e < 144; e += 128) scs[e] = 0.f;   // c-state fp32, padded stride 9
    if (L0) {                                            // zero the x pad cols [80,96)
        for (int e = tid; e < 256; e += 128) sxpad[(e >> 4) * 96 + 80 + (e & 15)] = 0;
    }

    // B fragments in registers. wave0 -> tile (i|f), wave1 -> tile (g|o).
    const int grow = wave * 1024 + ((n16 >> 3) * 512) + kwg * 8 + (n16 & 7);
    short8 bfr[KTIN + 16];
#pragma unroll
    for (int kt = 0; kt < KTIN; ++kt) {
        short8 v = {0,0,0,0,0,0,0,0};
        const int k = kt * 32 + koff;
        if (L0) { if (k + 8 <= 80) v = ld8bf(Wih + grow * 80 + k); }
        else    { v = ld8bf(Wih + (size_t)grow * 512 + k); }
        bfr[kt] = v;
    }
#pragma unroll
    for (int kt = 0; kt < 16; ++kt)
        bfr[KTIN + kt] = ld8bf(Whh + (size_t)grow * 512 + kt * 32 + koff);

    const int pb = (tid >> 4) & 3;
    const int cb = kwg * 8 + pb * 2;
    const float bI0 = bias[cb],        bI1 = bias[cb + 1];
    const float bF0 = bias[512 + cb],  bF1 = bias[512 + cb + 1];
    const float bG0 = bias[1024 + cb], bG1 = bias[1024 + cb + 1];
    const float bO0 = bias[1536 + cb], bO1 = bias[1536 + cb + 1];

    // flag slot bases: prev layer = slot(layer), own = slot(layer+1), next = slot(layer+2)
    const int* fP = flags + (layer * 64) * FLAG_STRIDE;
    const int* fO = flags + ((layer + 1) * 64) * FLAG_STRIDE;
    const int* fN = flags + ((layer + 2) * 64) * FLAG_STRIDE;
    int* myflag   = flags + ((layer + 1) * 64 + kwg) * FLAG_STRIDE;
    __syncthreads();

    for (int t = 0; t < 2000; ++t) {
        // ---- wait for producers / ring anti-dependency ----
        if (wave == 0) {
            int guard = 0;
            for (;;) {
                const int fp = __hip_atomic_load(fP + lane * FLAG_STRIDE, __ATOMIC_RELAXED, __HIP_MEMORY_SCOPE_AGENT);
                const int fo = __hip_atomic_load(fO + lane * FLAG_STRIDE, __ATOMIC_RELAXED, __HIP_MEMORY_SCOPE_AGENT);
                const int fn = __hip_atomic_load(fN + lane * FLAG_STRIDE, __ATOMIC_RELAXED, __HIP_MEMORY_SCOPE_AGENT);
                if (__all((fp >= t + 1) && (fo >= t) && (fn >= t - 7))) break;
                if (++guard > (1 << 22)) break;   // anti-hang escape
                __builtin_amdgcn_s_sleep(1);
            }
        }
        __syncthreads();

        // ---- stage h (and x) into LDS: one 16B bypass load per chunk ----
        const u16* hown = hbuf + ((size_t)(layer * NPAR + ((t + 7) & 7))) * 8192;
        short8 rin[8], rown[8];
        float4 xv0, xv1, xv2;
        if (L0) {
            const int e0 = tid, e1 = tid + 128, e2 = tid + 256;
            xv0 = *(const float4*)(x + ((size_t)(e0 / 20) * 2000 + t) * 80 + (e0 % 20) * 4);
            xv1 = *(const float4*)(x + ((size_t)(e1 / 20) * 2000 + t) * 80 + (e1 % 20) * 4);
            if (e2 < 320)
                xv2 = *(const float4*)(x + ((size_t)(e2 / 20) * 2000 + t) * 80 + (e2 % 20) * 4);
        } else {
            const u16* hin = hbuf + ((size_t)((layer - 1) * NPAR + (t & 7))) * 8192;
#pragma unroll
            for (int i = 0; i < 8; ++i) rin[i] = ldg16cv(hin + (tid + 128 * i) * 8);
        }
#pragma unroll
        for (int i = 0; i < 8; ++i) rown[i] = ldg16cv(hown + (tid + 128 * i) * 8);
        waitvm();
        if (L0) {
            const int e0 = tid, e1 = tid + 128, e2 = tid + 256;
            u32* d0 = (u32*)(sxpad + (e0 / 20) * 96 + (e0 % 20) * 4);
            d0[0] = pk2(xv0.x, xv0.y); d0[1] = pk2(xv0.z, xv0.w);
            u32* d1 = (u32*)(sxpad + (e1 / 20) * 96 + (e1 % 20) * 4);
            d1[0] = pk2(xv1.x, xv1.y); d1[1] = pk2(xv1.z, xv1.w);
            if (e2 < 320) {
                u32* d2 = (u32*)(sxpad + (e2 / 20) * 96 + (e2 % 20) * 4);
                d2[0] = pk2(xv2.x, xv2.y); d2[1] = pk2(xv2.z, xv2.w);
            }
        }
#pragma unroll
        for (int i = 0; i < 8; ++i) {
            const int c = tid + 128 * i;
            const int row = c >> 6, col8 = (c & 63) << 3;
            if (!L0) *(short8*)(AsIn + row * 520 + col8) = rin[i];
            *(short8*)(AsOwn + row * 520 + col8) = rown[i];
        }
        __syncthreads();

        // ---- gate GEMM ----
        f32x4 acc[4] = {{0,0,0,0},{0,0,0,0},{0,0,0,0},{0,0,0,0}};
#pragma unroll
        for (int kt = 0; kt < KTIN; ++kt) {
            short8 a;
            if (L0) a = *(const short8*)(sxpad + n16 * 96 + kt * 32 + koff);
            else    a = *(const short8*)(AsIn + n16 * 520 + kt * 32 + koff);
            acc[kt & 3] = mfma16(a, bfr[kt], acc[kt & 3]);
        }
#pragma unroll
        for (int kt = 0; kt < 16; ++kt) {
            short8 a = *(const short8*)(AsOwn + n16 * 520 + kt * 32 + koff);
            acc[(KTIN + kt) & 3] = mfma16(a, bfr[KTIN + kt], acc[(KTIN + kt) & 3]);
        }
        const f32x4 C = acc[0] + acc[1] + acc[2] + acc[3];
#pragma unroll
        for (int r = 0; r < 4; ++r)
            sC[(wave * 16 + quad * 4 + r) * 17 + n16] = C[r];   // [wave*16+batch][gate], padded
        __syncthreads();

        // ---- gate math + publish (wave0) ----
        if (tid < 64) {
            const int b = tid & 15, p = tid >> 4;
            u32 pk = 0;
#pragma unroll
            for (int e = 0; e < 2; ++e) {
                const int jl = p * 2 + e;
                const float gi = sC[b * 17 + jl]             + (e ? bI1 : bI0);
                const float gf = sC[b * 17 + 8 + jl]         + (e ? bF1 : bF0);
                const float gg = sC[(16 + b) * 17 + jl]      + (e ? bG1 : bG0);
                const float go = sC[(16 + b) * 17 + 8 + jl]  + (e ? bO1 : bO0);
                const float cp = scs[b * 9 + jl];
                const float cn = sigm(gf) * cp + sigm(gi) * tanhf(gg);
                const float hn = sigm(go) * tanhf(cn);
                scs[b * 9 + jl] = cn;
                pk |= ((u32)f2bf(hn)) << (16 * e);
                if (!L0 && layer == 2)
                    h3out[((size_t)(b * 2000 + t)) * 512 + kwg * 8 + p * 2 + e] = hn;
            }
            u32* hdst = (u32*)(hbuf + ((size_t)(layer * NPAR + (t & 7))) * 8192 + b * 512 + kwg * 8 + p * 2);
            __hip_atomic_store(hdst, pk, __ATOMIC_RELAXED, __HIP_MEMORY_SCOPE_AGENT);
            waitvm();  // ack at coherence point before flag
            if (tid == 0)
                __hip_atomic_store(myflag, t + 1, __ATOMIC_RELAXED, __HIP_MEMORY_SCOPE_AGENT);
        }
    }
}

__global__ __launch_bounds__(128, 1) void k_frame_lstm(
    const float* __restrict__ x,
    const float* __restrict__ Wih0, const float* __restrict__ Whh0, const float* __restrict__ b0,
    const float* __restrict__ Wih1, const float* __restrict__ Whh1, const float* __restrict__ b1,
    const float* __restrict__ Wih2, const float* __restrict__ Whh2, const float* __restrict__ b2,
    u16* hbuf, int* flags, float* h3out)
{
    __shared__ __align__(16) u16 sxpad[16 * 96];
    __shared__ __align__(16) u16 AsIn[16 * 520];
    __shared__ __align__(16) u16 AsOwn[16 * 520];
    __shared__ float sC[32 * 17];
    __shared__ float scs[16 * 9];
    const int wgid = blockIdx.x;
    const int layer = wgid >> 6;
    const int kwg = wgid & 63;
    if (layer == 0)      frame_body<3,  true >(0, kwg, Wih0, Whh0, b0, x, hbuf, flags, h3out, sC, scs, sxpad, AsIn, AsOwn);
    else if (layer == 1) frame_body<16, false>(1, kwg, Wih1, Whh1, b1, x, hbuf, flags, h3out, sC, scs, sxpad, AsIn, AsOwn);
    else                 frame_body<16, false>(2, kwg, Wih2, Whh2, b2, x, hbuf, flags, h3out, sC, scs, sxpad, AsIn, AsOwn);
}

// ---------------------------------------------------------------------------
// Persistent word LSTM: 32 WGs x 128 threads, 100 steps, H=256, K=256+256.
// Same flag scheme (own-layer only), ring-8 h buffer, 16B bypass loads.
// ---------------------------------------------------------------------------
__global__ __launch_bounds__(128, 1) void k_word_lstm(
    const u16* __restrict__ rW, const float* __restrict__ Wih,
    const float* __restrict__ Whh, const float* __restrict__ bias,
    u16* __restrict__ hbufw, int* __restrict__ flags, float* __restrict__ hseq)
{
    __shared__ float sC[32 * 17];
    __shared__ float scs[16 * 9];
    const int tid = threadIdx.x;
    const int lane = tid & 63;
    const int wave = tid >> 6;
    const int n16 = lane & 15;
    const int quad = lane >> 4;
    const int koff = quad * 8;
    const int kwg = blockIdx.x;  // 0..31

    for (int e = tid; e < 144; e += 128) scs[e] = 0.f;
    const int grow = wave * 512 + ((n16 >> 3) * 256) + kwg * 8 + (n16 & 7);
    short8 bfr[16];
#pragma unroll
    for (int kt = 0; kt < 8; ++kt) bfr[kt]     = ld8bf(Wih + (size_t)grow * 256 + kt * 32 + koff);
#pragma unroll
    for (int kt = 0; kt < 8; ++kt) bfr[8 + kt] = ld8bf(Whh + (size_t)grow * 256 + kt * 32 + koff);
    const int pb = (tid >> 4) & 3;
    const int cb = kwg * 8 + pb * 2;
    const float bI0 = bias[cb],       bI1 = bias[cb + 1];
    const float bF0 = bias[256 + cb], bF1 = bias[256 + cb + 1];
    const float bG0 = bias[512 + cb], bG1 = bias[512 + cb + 1];
    const float bO0 = bias[768 + cb], bO1 = bias[768 + cb + 1];
    const int* fO = flags + 320 * FLAG_STRIDE;
    int* myflag   = flags + (320 + kwg) * FLAG_STRIDE;
    __syncthreads();
    const int aoff = n16 * 256 + koff;

    for (int t = 0; t < 100; ++t) {
        if (wave == 0) {
            int guard = 0;
            for (;;) {
                const int fo = (lane < 32)
                    ? __hip_atomic_load(fO + lane * FLAG_STRIDE, __ATOMIC_RELAXED, __HIP_MEMORY_SCOPE_AGENT)
                    : BIGF;
                if (__all(fo >= t)) break;
                if (++guard > (1 << 22)) break;
                __builtin_amdgcn_s_sleep(1);
            }
        }
        __syncthreads();
        const u16* hown = hbufw + ((size_t)((t + 7) & 7)) * 4096;
        short8 ha[8];
#pragma unroll
        for (int kt = 0; kt < 8; ++kt) ha[kt] = ldg16cv(hown + aoff + kt * 32);
        f32x4 acc[4] = {{0,0,0,0},{0,0,0,0},{0,0,0,0},{0,0,0,0}};
#pragma unroll
        for (int kt = 0; kt < 8; ++kt) {
            short8 a = *(const short8*)(rW + ((size_t)(n16 * 100 + t)) * 256 + koff + kt * 32);
            acc[kt & 3] = mfma16(a, bfr[kt], acc[kt & 3]);
        }
        waitvm();
#pragma unroll
        for (int kt = 0; kt < 8; ++kt)
            acc[kt & 3] = mfma16(ha[kt], bfr[8 + kt], acc[kt & 3]);
        const f32x4 C = acc[0] + acc[1] + acc[2] + acc[3];
#pragma unroll
        for (int r = 0; r < 4; ++r) sC[(wave * 16 + quad * 4 + r) * 17 + n16] = C[r];
        __syncthreads();
        if (tid < 64) {
            const int b = tid & 15, p = tid >> 4;
            u32 pk = 0;
#pragma unroll
            for (int e = 0; e < 2; ++e) {
                const int jl = p * 2 + e;
                const float gi = sC[b * 17 + jl]            + (e ? bI1 : bI0);
                const float gf = sC[b * 17 + 8 + jl]        + (e ? bF1 : bF0);
                const float gg = sC[(16 + b) * 17 + jl]     + (e ? bG1 : bG0);
                const float go = sC[(16 + b) * 17 + 8 + jl] + (e ? bO1 : bO0);
                const float cp = scs[b * 9 + jl];
                const float cn = sigm(gf) * cp + sigm(gi) * tanhf(gg);
                const float hn = sigm(go) * tanhf(cn);
                scs[b * 9 + jl] = cn;
                pk |= ((u32)f2bf(hn)) << (16 * e);
                hseq[((size_t)(b * 100 + t)) * 256 + kwg * 8 + p * 2 + e] = hn;
            }
            u32* hdst = (u32*)(hbufw + ((size_t)(t & 7)) * 4096 + b * 256 + kwg * 8 + p * 2);
            __hip_atomic_store(hdst, pk, __ATOMIC_RELAXED, __HIP_MEMORY_SCOPE_AGENT);
            waitvm();
            if (tid == 0)
                __hip_atomic_store(myflag, t + 1, __ATOMIC_RELAXED, __HIP_MEMORY_SCOPE_AGENT);
        }
    }
}

// ---------------------------------------------------------------------------
// Ragged tail-mean pooling from fp32 h3 (in d_out): reps fp32 (ws)
// ---------------------------------------------------------------------------
__global__ void k_pool(const float* __restrict__ h3, const int* __restrict__ x_lens,
                       const int* __restrict__ wstarts, const int* __restrict__ wends,
                       const int* __restrict__ wlens, const int* __restrict__ tailp,
                       float* __restrict__ reps)
{
    const int rw = blockIdx.x;
    const int b = rw / 100, w = rw - b * 100;
    const int tid = threadIdx.x;
    const int xl = x_lens[b];
    const int we = wends[rw];
    const int s0 = wstarts[rw];
    const int wl = wlens[b];
    const int tail = tailp[0];
    int ef = we < xl ? we : xl;
    int sf = s0 > 0 ? s0 : 0;
    int i0 = ef - tail; if (i0 < sf) i0 = sf;
    const bool valid = (w < wl) && (we > 0) && (ef > sf) && (ef > i0);
    float a0 = 0.f, a1 = 0.f;
    if (valid) {
        for (int t = i0; t < ef; ++t) {
            const float* hp = h3 + ((size_t)(b * 2000 + t)) * 512;
            a0 += hp[tid];
            a1 += hp[tid + 256];
        }
        const float inv = 1.f / (float)(ef - i0);
        a0 *= inv; a1 *= inv;
    }
    reps[(size_t)rw * 512 + tid] = a0;
    reps[(size_t)rw * 512 + tid + 256] = a1;
}

// ---------------------------------------------------------------------------
// In-place frame projection: y[b,t,:] = mask(h3[b,t,:]) @ fpW^T + fpb (fp32)
// ---------------------------------------------------------------------------
__global__ __launch_bounds__(256, 2) void k_frame_proj(
    float* __restrict__ y, const int* __restrict__ x_lens,
    const u16* __restrict__ fpWb, const float* __restrict__ fpb)
{
    __shared__ __align__(16) u16 As[16 * 520];
    const int tid = threadIdx.x, lane = tid & 63, wave = tid >> 6;
    const int n16 = lane & 15, quad = lane >> 4, koff = quad * 8;
    const int blk = blockIdx.x;          // 2000 blocks: 125 per batch
    const int b = blk / 125;
    const int t0 = (blk - b * 125) * 16;
    const int xl = x_lens[b];
    for (int c = tid; c < 2048; c += 256) {      // 16 rows x 128 float4
        const int row = c >> 7;
        const int q = c & 127;
        const int t = t0 + row;
        float4 v = {0.f, 0.f, 0.f, 0.f};
        if (t < xl) v = *(const float4*)(y + ((size_t)(b * 2000 + t)) * 512 + q * 4);
        u32* d = (u32*)(As + row * 520 + q * 4);
        d[0] = pk2(v.x, v.y);
        d[1] = pk2(v.z, v.w);
    }
    __syncthreads();
    const size_t rowbase = (size_t)b * 2000 + t0;
    for (int ct = 0; ct < 8; ++ct) {
        const int col0 = (wave * 8 + ct) * 16;
        f32x4 acc = {0, 0, 0, 0};
#pragma unroll
        for (int kt = 0; kt < 16; ++kt) {
            short8 a = *(const short8*)(As + n16 * 520 + kt * 32 + koff);
            short8 wv = *(const short8*)(fpWb + ((size_t)(col0 + n16)) * 512 + kt * 32 + koff);
            acc = mfma16(a, wv, acc);
        }
        const float bn = fpb[col0 + n16];
#pragma unroll
        for (int r = 0; r < 4; ++r) {
            const int m = quad * 4 + r;
            y[(rowbase + m) * 512 + col0 + n16] = acc[r] + bn;
        }
    }
}

// ---------------------------------------------------------------------------
// word_proj: Linear(512->256) + LayerNorm + exact GELU per (b,w) row.
// ---------------------------------------------------------------------------
__global__ void k_word_proj(const float* __restrict__ reps, const float* __restrict__ wpW,
                            const float* __restrict__ wpb, const float* __restrict__ lnW,
                            const float* __restrict__ lnB, u16* __restrict__ rW)
{
    __shared__ float sx[512];
    __shared__ float red[512];
    const int tid = threadIdx.x;
    const int row = blockIdx.x;
    for (int k = tid; k < 512; k += 256) sx[k] = reps[(size_t)row * 512 + k];
    __syncthreads();
    float acc = wpb[tid];
    const float4* wr = (const float4*)(wpW + (size_t)tid * 512);
    for (int k4 = 0; k4 < 128; ++k4) {
        const float4 w = wr[k4];
        acc += sx[k4 * 4] * w.x + sx[k4 * 4 + 1] * w.y + sx[k4 * 4 + 2] * w.z + sx[k4 * 4 + 3] * w.w;
    }
    red[tid] = acc; red[256 + tid] = acc * acc;
    __syncthreads();
    for (int s = 128; s > 0; s >>= 1) {
        if (tid < s) { red[tid] += red[tid + s]; red[256 + tid] += red[256 + tid + s]; }
        __syncthreads();
    }
    const float mu = red[0] * (1.f / 256.f);
    float var = red[256] * (1.f / 256.f) - mu * mu;
    if (var < 0.f) var = 0.f;
    const float xn = (acc - mu) * rsqrtf(var + 1e-5f);
    const float yv = xn * lnW[tid] + lnB[tid];
    const float g = 0.5f * yv * (1.0f + erff(yv * 0.70710678118654752f));
    rW[(size_t)row * 256 + tid] = f2bf(g);
}

// ---------------------------------------------------------------------------
// pred_sem = mask(hseq) @ spW^T + spb  (fp32 vector math)
// ---------------------------------------------------------------------------
__global__ void k_pred(const float* __restrict__ hseq, const int* __restrict__ wlens,
                       const float* __restrict__ spW, const float* __restrict__ spb,
                       float* __restrict__ out)
{
    __shared__ float sh[256];
    const int tid = threadIdx.x;
    const int rw = blockIdx.x;
    const int b = rw / 100, w = rw - b * 100;
    int wl = wlens[b]; if (wl < 1) wl = 1;
    const bool valid = (w < wl);
    sh[tid] = valid ? hseq[(size_t)rw * 256 + tid] : 0.f;
    __syncthreads();
    for (int o = tid; o < 512; o += 256) {
        float acc = spb[o];
        const float4* wr = (const float4*)(spW + (size_t)o * 256);
        for (int k4 = 0; k4 < 64; ++k4) {
            const float4 wv = wr[k4];
            acc += sh[k4 * 4] * wv.x + sh[k4 * 4 + 1] * wv.y + sh[k4 * 4 + 2] * wv.z + sh[k4 * 4 + 3] * wv.w;
        }
        out[PS_OFF + (size_t)rw * 512 + o] = acc;
    }
}

__global__ void k_xlens(const int* __restrict__ x_lens, float* __restrict__ out)
{
    const int tid = threadIdx.x;
    if (tid < 16) out[XL_OFF + tid] = (float)x_lens[tid];
}

// Pre-cast fpW (512x512 fp32) -> bf16
__global__ void k_cvt(const float* __restrict__ src, u16* __restrict__ dst)
{
    const int e = blockIdx.x * 256 + threadIdx.x;   // 65536 float4s
    const float4 v = *(const float4*)(src + (size_t)e * 4);
    u32* d = (u32*)(dst + (size_t)e * 4);
    d[0] = pk2(v.x, v.y);
    d[1] = pk2(v.z, v.w);
}

// Init flags (with BIG sentinels for dummy layers) + zero h rings.
// Covers bytes [0, 491520): 480 blocks x 256 threads x 1 u32.
__global__ void k_init(u32* __restrict__ p)
{
    const int idx = blockIdx.x * 256 + threadIdx.x;
    u32 v = 0u;
    if (idx < 8192) {                      // flag area (32 KB)
        const int slot = idx >> 4;
        if (slot < 64 || (slot >= 256 && slot < 320)) v = (u32)BIGF;
    }
    p[idx] = v;
}

// ---------------------------------------------------------------------------
extern "C" void kernel_launch(void* const* d_in, const int* in_sizes, int n_in,
                              void* d_out, int out_size, void* d_ws, size_t ws_size,
                              hipStream_t stream)
{
    (void)in_sizes; (void)n_in; (void)out_size; (void)ws_size;
    const float* x    = (const float*)d_in[0];
    const int* x_lens = (const int*)d_in[1];
    const int* wstart = (const int*)d_in[2];
    const int* wend   = (const int*)d_in[3];
    const int* wlen   = (const int*)d_in[4];
    const int* tailp  = (const int*)d_in[5];
    const float* Wih0 = (const float*)d_in[6];
    const float* Whh0 = (const float*)d_in[7];
    const float* b0   = (const float*)d_in[8];
    const float* Wih1 = (const float*)d_in[9];
    const float* Whh1 = (const float*)d_in[10];
    const float* b1   = (const float*)d_in[11];
    const float* Wih2 = (const float*)d_in[12];
    const float* Whh2 = (const float*)d_in[13];
    const float* b2   = (const float*)d_in[14];
    const float* fpW  = (const float*)d_in[15];
    const float* fpb  = (const float*)d_in[16];
    const float* wpW  = (const float*)d_in[17];
    const float* wpb  = (const float*)d_in[18];
    const float* lnW  = (const float*)d_in[19];
    const float* lnB  = (const float*)d_in[20];
    const float* wWih = (const float*)d_in[21];
    const float* wWhh = (const float*)d_in[22];
    const float* wb   = (const float*)d_in[23];
    const float* spW  = (const float*)d_in[24];
    const float* spb  = (const float*)d_in[25];

    float* out = (float*)d_out;
    char* ws = (char*)d_ws;
    int* flags  = (int*)(ws + WS_FLAGS);
    u16* hbufF  = (u16*)(ws + WS_HBUF_F);
    u16* hbufW  = (u16*)(ws + WS_HBUF_W);
    float* reps = (float*)(ws + WS_REPS);
    u16* rW     = (u16*)(ws + WS_RW);
    float* hseq = (float*)(ws + WS_HSEQ);
    u16* fpWb   = (u16*)(ws + WS_FPWB);

    k_init<<<480, 256, 0, stream>>>((u32*)d_ws);
    k_cvt<<<256, 256, 0, stream>>>(fpW, fpWb);
    k_frame_lstm<<<192, 128, 0, stream>>>(x, Wih0, Whh0, b0, Wih1, Whh1, b1,
                                          Wih2, Whh2, b2, hbufF, flags, out);
    k_pool<<<1600, 256, 0, stream>>>(out, x_lens, wstart, wend, wlen, tailp, reps);
    k_frame_proj<<<2000, 256, 0, stream>>>(out, x_lens, fpWb, fpb);  // after k_pool (in-place)
    k_word_proj<<<1600, 256, 0, stream>>>(reps, wpW, wpb, lnW, lnB, rW);
    k_word_lstm<<<32, 128, 0, stream>>>(rW, wWih, wWhh, wb, hbufW, flags, hseq);
    k_pred<<<1600, 256, 0, stream>>>(hseq, wlen, spW, spb, out);
    k_xlens<<<1, 64, 0, stream>>>(x_lens, out);
}